// Round 7
// baseline (1386.302 us; speedup 1.0000x reference)
//
#include <hip/hip_runtime.h>
#include <cstddef>

// PseudoSpectra2d: out = B1 @ (LocalConv3x3_posdep( pad(A1[:64]@u@A2[:64]^T) , W)) @ B2^T
// B=16, CIN=COUT=32, H=W=128, M1=M2=64, KH=KW=3, pad=1
// ws: bpi [16][32][64][64] f32 (8 MB) | out2 [16][32][64][64] f32 (8 MB)

#define NB 16
#define NCIN 32
#define NCOUT 32

typedef float f32x4 __attribute__((ext_vector_type(4)));

__device__ __forceinline__ float dpp_shr1(float x) {  // lane i <- lane i-1 (16-lane rows), edge -> 0
  int r = __builtin_amdgcn_update_dpp(0, __float_as_int(x), 0x111, 0xF, 0xF, true);
  return __int_as_float(r);
}
__device__ __forceinline__ float dpp_shl1(float x) {  // lane i <- lane i+1 (16-lane rows), edge -> 0
  int r = __builtin_amdgcn_update_dpp(0, __float_as_int(x), 0x101, 0xF, 0xF, true);
  return __int_as_float(r);
}
__device__ __forceinline__ void nt_store4(float* p, float a, float b, float c, float d) {
  f32x4 v; v.x = a; v.y = b; v.z = c; v.w = d;
  __builtin_nontemporal_store(v, (f32x4*)p);
}

// ---------------------------------------------------------------------------
// K1: per (b,c): T[h][k] = sum_w u[h][w]*A2[k][w]; bp[m][k] = sum_h A1[m][h]*T[h][k]
// Global streams (u, A1) 2-stage prefetched; A2^T / T via LDS. 512 blocks, 2/CU.
// ---------------------------------------------------------------------------
__global__ __launch_bounds__(256) void k1_spectral(const float* __restrict__ u,
                                                   const float* __restrict__ A1,
                                                   const float* __restrict__ A2,
                                                   float* __restrict__ bpi) {
  __shared__ float a2t[128 * 68];   // [w][k], stride 68
  __shared__ float t_s[128 * 68];   // [h][k], stride 68
  const int tid = threadIdx.x;
  const int bc = blockIdx.x;        // b*32 + c
  const float* up = u + (size_t)bc * 16384;

  // stage A2^T: a2t[w][k] = A2[k][w]  (k < 64)
#pragma unroll
  for (int it = 0; it < 8; ++it) {
    int f = it * 256 + tid;
    int k = f >> 5;
    int w4 = (f & 31) * 4;
    float4 v = *(const float4*)(A2 + k * 128 + w4);
    a2t[(w4 + 0) * 68 + k] = v.x;
    a2t[(w4 + 1) * 68 + k] = v.y;
    a2t[(w4 + 2) * 68 + k] = v.z;
    a2t[(w4 + 3) * 68 + k] = v.w;
  }
  __syncthreads();

  // Phase B: T[h][k], tile 8h x 4k (threads (16,16)); u prefetched 1 step ahead.
  {
    const int h0 = (tid >> 4) * 8;
    const int k0 = (tid & 15) * 4;
    float acc[8][4] = {};
    float4 uvA[8], uvB[8];
#pragma unroll
    for (int i = 0; i < 8; ++i) uvA[i] = *(const float4*)(up + (h0 + i) * 128 + 0);

#pragma unroll 1
    for (int w4 = 0; w4 < 128; w4 += 8) {
      // prefetch w4+4
#pragma unroll
      for (int i = 0; i < 8; ++i) uvB[i] = *(const float4*)(up + (h0 + i) * 128 + w4 + 4);
      // compute with uvA @ w4
      {
        float4 av[4];
#pragma unroll
        for (int dw = 0; dw < 4; ++dw) av[dw] = *(const float4*)(a2t + (w4 + dw) * 68 + k0);
#pragma unroll
        for (int i = 0; i < 8; ++i) {
          const float* up_ = (const float*)&uvA[i];
#pragma unroll
          for (int dw = 0; dw < 4; ++dw) {
            const float* ap = (const float*)&av[dw];
            float uval = up_[dw];
#pragma unroll
            for (int j = 0; j < 4; ++j) acc[i][j] += uval * ap[j];
          }
        }
      }
      // prefetch w4+8
      if (w4 + 8 < 128) {
#pragma unroll
        for (int i = 0; i < 8; ++i) uvA[i] = *(const float4*)(up + (h0 + i) * 128 + w4 + 8);
      }
      // compute with uvB @ w4+4
      {
        float4 av[4];
#pragma unroll
        for (int dw = 0; dw < 4; ++dw) av[dw] = *(const float4*)(a2t + (w4 + 4 + dw) * 68 + k0);
#pragma unroll
        for (int i = 0; i < 8; ++i) {
          const float* up_ = (const float*)&uvB[i];
#pragma unroll
          for (int dw = 0; dw < 4; ++dw) {
            const float* ap = (const float*)&av[dw];
            float uval = up_[dw];
#pragma unroll
            for (int j = 0; j < 4; ++j) acc[i][j] += uval * ap[j];
          }
        }
      }
    }
#pragma unroll
    for (int i = 0; i < 8; ++i)
      *(float4*)(t_s + (h0 + i) * 68 + k0) =
          make_float4(acc[i][0], acc[i][1], acc[i][2], acc[i][3]);
  }
  __syncthreads();

  // Phase C: bp[m][k], tile 4m x 4k (threads (16,16)); A1 prefetched 1 step ahead.
  {
    const int m0 = (tid >> 4) * 4;
    const int k0 = (tid & 15) * 4;
    float acc[4][4] = {};
    float4 aA[4], aB[4];
#pragma unroll
    for (int i = 0; i < 4; ++i) aA[i] = *(const float4*)(A1 + (m0 + i) * 128 + 0);

#pragma unroll 1
    for (int h4 = 0; h4 < 128; h4 += 8) {
#pragma unroll
      for (int i = 0; i < 4; ++i) aB[i] = *(const float4*)(A1 + (m0 + i) * 128 + h4 + 4);
      {
        float4 tv[4];
#pragma unroll
        for (int dh = 0; dh < 4; ++dh) tv[dh] = *(const float4*)(t_s + (h4 + dh) * 68 + k0);
#pragma unroll
        for (int i = 0; i < 4; ++i) {
          const float* ap = (const float*)&aA[i];
#pragma unroll
          for (int dh = 0; dh < 4; ++dh) {
            const float* tp = (const float*)&tv[dh];
            float aval = ap[dh];
#pragma unroll
            for (int j = 0; j < 4; ++j) acc[i][j] += aval * tp[j];
          }
        }
      }
      if (h4 + 8 < 128) {
#pragma unroll
        for (int i = 0; i < 4; ++i) aA[i] = *(const float4*)(A1 + (m0 + i) * 128 + h4 + 8);
      }
      {
        float4 tv[4];
#pragma unroll
        for (int dh = 0; dh < 4; ++dh) tv[dh] = *(const float4*)(t_s + (h4 + 4 + dh) * 68 + k0);
#pragma unroll
        for (int i = 0; i < 4; ++i) {
          const float* ap = (const float*)&aB[i];
#pragma unroll
          for (int dh = 0; dh < 4; ++dh) {
            const float* tp = (const float*)&tv[dh];
            float aval = ap[dh];
#pragma unroll
            for (int j = 0; j < 4; ++j) acc[i][j] += aval * tp[j];
          }
        }
      }
    }
    float* bp = bpi + (size_t)bc * 4096;
#pragma unroll
    for (int i = 0; i < 4; ++i)
      nt_store4(bp + (m0 + i) * 64 + k0, acc[i][0], acc[i][1], acc[i][2], acc[i][3]);
  }
}

// ---------------------------------------------------------------------------
// K2: out2[b][o][xi][xj] = sum_{c,ki,kj} xpad(b,c,xi-1+ki,xj-1+kj) * W[c*9+ki*3+kj][o][xi*64+xj]
// No LDS/barriers. Unroll-2 double-buffered register pipeline: loads for c+1
// issued one full compute-block before their use (hides L2/L3/HBM latency).
// Grid (64 xi XCD-swizzled, 8 og) x 256 thr; ~230 VGPR -> 2 blocks/CU.
// ---------------------------------------------------------------------------
struct K2Buf {
  float4 xv[2][3];
  float4 wr[9][2];
};

__device__ __forceinline__ void k2_load(K2Buf& B, const float* __restrict__ bpi,
                                        const float* __restrict__ Wt,
                                        int c, int xi, int b0, int o0, int xjg) {
#pragma unroll
  for (int ki = 0; ki < 3; ++ki) {
    const int row = xi - 1 + ki;
    const bool valid = (row >= 0) && (row < 64);   // wave-uniform
#pragma unroll
    for (int rb = 0; rb < 2; ++rb) {
      if (valid)
        B.xv[rb][ki] = *(const float4*)(bpi +
            (((size_t)(b0 + rb) * NCIN + c) * 64 + row) * 64 + xjg * 4);
      else
        B.xv[rb][ki] = make_float4(0.f, 0.f, 0.f, 0.f);
    }
  }
  const float* wbase = Wt + (((size_t)c * 9) * NCOUT + o0) * 4096 + xi * 64 + xjg * 4;
#pragma unroll
  for (int t = 0; t < 9; ++t)
#pragma unroll
    for (int oo = 0; oo < 2; ++oo)
      B.wr[t][oo] = *(const float4*)(wbase + ((size_t)t * NCOUT + oo) * 4096);
}

__device__ __forceinline__ void k2_compute(const K2Buf& B, float acc[2][2][4]) {
#pragma unroll
  for (int ki = 0; ki < 3; ++ki) {
#pragma unroll
    for (int rb = 0; rb < 2; ++rb) {
      float xw[6];
      xw[1] = B.xv[rb][ki].x; xw[2] = B.xv[rb][ki].y;
      xw[3] = B.xv[rb][ki].z; xw[4] = B.xv[rb][ki].w;
      xw[0] = dpp_shr1(B.xv[rb][ki].w);   // col xj-1 (0 at left edge = pad)
      xw[5] = dpp_shl1(B.xv[rb][ki].x);   // col xj+4 (0 at right edge = pad)
#pragma unroll
      for (int kj = 0; kj < 3; ++kj) {
        const int t = ki * 3 + kj;
#pragma unroll
        for (int oo = 0; oo < 2; ++oo) {
          const float* w = (const float*)&B.wr[t][oo];
#pragma unroll
          for (int x = 0; x < 4; ++x)
            acc[rb][oo][x] += xw[x + kj] * w[x];
        }
      }
    }
  }
}

__global__ __launch_bounds__(256, 2) void k2_conv(const float* __restrict__ bpi,
                                                  const float* __restrict__ Wt,
                                                  float* __restrict__ out2) {
  const int tid = threadIdx.x;
  const int lane = tid & 63;
  const int wv = tid >> 6;
  const int xjg = lane & 15;
  const int lbg = lane >> 4;
  const int bid = blockIdx.x;
  const int xi = ((bid & 7) << 3) | (bid >> 3);   // XCD-swizzle
  const int og = blockIdx.y;                       // 0..7
  const int bg = wv >> 1;
  const int op = wv & 1;
  const int o0 = og * 4 + op * 2;
  const int b0 = bg * 8 + lbg * 2;

  float acc[2][2][4] = {};
  K2Buf A, Bb;
  k2_load(A,  bpi, Wt, 0, xi, b0, o0, xjg);
  k2_load(Bb, bpi, Wt, 1, xi, b0, o0, xjg);

#pragma unroll 1
  for (int c = 0; c < NCIN; c += 2) {
    k2_compute(A, acc);
    if (c + 2 < NCIN) k2_load(A, bpi, Wt, c + 2, xi, b0, o0, xjg);
    k2_compute(Bb, acc);
    if (c + 3 < NCIN) k2_load(Bb, bpi, Wt, c + 3, xi, b0, o0, xjg);
  }

#pragma unroll
  for (int rb = 0; rb < 2; ++rb)
#pragma unroll
    for (int oo = 0; oo < 2; ++oo)
      nt_store4(out2 + ((size_t)(b0 + rb) * NCOUT + (o0 + oo)) * 4096 + xi * 64 + xjg * 4,
                acc[rb][oo][0], acc[rb][oo][1], acc[rb][oo][2], acc[rb][oo][3]);
}

// ---------------------------------------------------------------------------
// K3: per (b,o): T2[m][w] = sum_k out2[m][k]*B2[w][k];  R[h][w] = sum_m B1[h][m]*T2[m][w]
// out2 / B1 streams 2-stage prefetched. Phase C3 w-tile split (w0, w0+64) to
// reduce t2 LDS read conflicts to 2-way. LDS 66 KB -> 2 blocks/CU.
// ---------------------------------------------------------------------------
__global__ __launch_bounds__(256) void k3_recon(const float* __restrict__ out2,
                                                const float* __restrict__ B1,
                                                const float* __restrict__ B2,
                                                float* __restrict__ outp) {
  __shared__ float b2t[64 * 132];    // [k][w], stride 132
  __shared__ float t2[64 * 132];     // [m][w], stride 132
  const int tid = threadIdx.x;
  const int bc = blockIdx.x;         // b*32 + o

  // stage B2^T: b2t[k][w] = B2[w][k]
#pragma unroll
  for (int it = 0; it < 8; ++it) {
    int f = it * 256 + tid;
    int w = f >> 4;
    int k4 = (f & 15) * 4;
    float4 v = *(const float4*)(B2 + w * 64 + k4);
    b2t[(k4 + 0) * 132 + w] = v.x;
    b2t[(k4 + 1) * 132 + w] = v.y;
    b2t[(k4 + 2) * 132 + w] = v.z;
    b2t[(k4 + 3) * 132 + w] = v.w;
  }
  __syncthreads();

  // Phase B3: T2[m][w], tile 8m x 4w (threads (8,32)); out2 prefetched.
  {
    const int m0 = (tid >> 5) * 8;
    const int w0 = (tid & 31) * 4;
    float acc[8][4] = {};
    const float* o2 = out2 + (size_t)bc * 4096;
    float4 aA[8], aB[8];
#pragma unroll
    for (int i = 0; i < 8; ++i) aA[i] = *(const float4*)(o2 + (m0 + i) * 64 + 0);

#pragma unroll 1
    for (int k4 = 0; k4 < 64; k4 += 8) {
#pragma unroll
      for (int i = 0; i < 8; ++i) aB[i] = *(const float4*)(o2 + (m0 + i) * 64 + k4 + 4);
      {
        float4 bb[4];
#pragma unroll
        for (int dk = 0; dk < 4; ++dk) bb[dk] = *(const float4*)(b2t + (k4 + dk) * 132 + w0);
#pragma unroll
        for (int i = 0; i < 8; ++i) {
          const float* ap = (const float*)&aA[i];
#pragma unroll
          for (int dk = 0; dk < 4; ++dk) {
            const float* bp = (const float*)&bb[dk];
            float aval = ap[dk];
#pragma unroll
            for (int j = 0; j < 4; ++j) acc[i][j] += aval * bp[j];
          }
        }
      }
      if (k4 + 8 < 64) {
#pragma unroll
        for (int i = 0; i < 8; ++i) aA[i] = *(const float4*)(o2 + (m0 + i) * 64 + k4 + 8);
      }
      {
        float4 bb[4];
#pragma unroll
        for (int dk = 0; dk < 4; ++dk) bb[dk] = *(const float4*)(b2t + (k4 + 4 + dk) * 132 + w0);
#pragma unroll
        for (int i = 0; i < 8; ++i) {
          const float* ap = (const float*)&aB[i];
#pragma unroll
          for (int dk = 0; dk < 4; ++dk) {
            const float* bp = (const float*)&bb[dk];
            float aval = ap[dk];
#pragma unroll
            for (int j = 0; j < 4; ++j) acc[i][j] += aval * bp[j];
          }
        }
      }
    }
    __syncthreads();
#pragma unroll
    for (int i = 0; i < 8; ++i)
      *(float4*)(t2 + (m0 + i) * 132 + w0) =
          make_float4(acc[i][0], acc[i][1], acc[i][2], acc[i][3]);
  }
  __syncthreads();

  // Phase C3: R[h][w], tile 8h x (4+4)w at (w0, w0+64) (threads (16,16)); B1 prefetched.
  {
    const int h0 = (tid >> 4) * 8;
    const int w0 = (tid & 15) * 4;       // cols w0..w0+3 and w0+64..w0+67
    float acc[8][8] = {};
    float4 aA[8], aB[8];
#pragma unroll
    for (int i = 0; i < 8; ++i) aA[i] = *(const float4*)(B1 + (h0 + i) * 64 + 0);

#pragma unroll 1
    for (int m = 0; m < 64; m += 8) {
#pragma unroll
      for (int i = 0; i < 8; ++i) aB[i] = *(const float4*)(B1 + (h0 + i) * 64 + m + 4);
      {
        float4 bb0[4], bb1[4];
#pragma unroll
        for (int dm = 0; dm < 4; ++dm) {
          bb0[dm] = *(const float4*)(t2 + (m + dm) * 132 + w0);
          bb1[dm] = *(const float4*)(t2 + (m + dm) * 132 + w0 + 64);
        }
#pragma unroll
        for (int i = 0; i < 8; ++i) {
          const float* ap = (const float*)&aA[i];
#pragma unroll
          for (int dm = 0; dm < 4; ++dm) {
            const float* b0p = (const float*)&bb0[dm];
            const float* b1p = (const float*)&bb1[dm];
            float aval = ap[dm];
#pragma unroll
            for (int j = 0; j < 4; ++j) {
              acc[i][j]     += aval * b0p[j];
              acc[i][4 + j] += aval * b1p[j];
            }
          }
        }
      }
      if (m + 8 < 64) {
#pragma unroll
        for (int i = 0; i < 8; ++i) aA[i] = *(const float4*)(B1 + (h0 + i) * 64 + m + 8);
      }
      {
        float4 bb0[4], bb1[4];
#pragma unroll
        for (int dm = 0; dm < 4; ++dm) {
          bb0[dm] = *(const float4*)(t2 + (m + 4 + dm) * 132 + w0);
          bb1[dm] = *(const float4*)(t2 + (m + 4 + dm) * 132 + w0 + 64);
        }
#pragma unroll
        for (int i = 0; i < 8; ++i) {
          const float* ap = (const float*)&aB[i];
#pragma unroll
          for (int dm = 0; dm < 4; ++dm) {
            const float* b0p = (const float*)&bb0[dm];
            const float* b1p = (const float*)&bb1[dm];
            float aval = ap[dm];
#pragma unroll
            for (int j = 0; j < 4; ++j) {
              acc[i][j]     += aval * b0p[j];
              acc[i][4 + j] += aval * b1p[j];
            }
          }
        }
      }
    }
    float* rp = outp + (size_t)bc * 16384;
#pragma unroll
    for (int i = 0; i < 8; ++i) {
      *(float4*)(rp + (h0 + i) * 128 + w0) =
          make_float4(acc[i][0], acc[i][1], acc[i][2], acc[i][3]);
      *(float4*)(rp + (h0 + i) * 128 + w0 + 64) =
          make_float4(acc[i][4], acc[i][5], acc[i][6], acc[i][7]);
    }
  }
}

extern "C" void kernel_launch(void* const* d_in, const int* in_sizes, int n_in,
                              void* d_out, int out_size, void* d_ws, size_t ws_size,
                              hipStream_t stream) {
  (void)in_sizes; (void)n_in; (void)out_size; (void)ws_size;
  const float* u  = (const float*)d_in[0];
  const float* A1 = (const float*)d_in[1];
  const float* A2 = (const float*)d_in[2];
  const float* B1 = (const float*)d_in[3];
  const float* B2 = (const float*)d_in[4];
  const float* Wt = (const float*)d_in[5];
  float* out = (float*)d_out;

  const size_t SEG = (size_t)NB * NCIN * 4096 * sizeof(float);   // 8 MB
  float* bpi  = (float*)d_ws;
  float* out2 = (float*)((char*)d_ws + SEG);

  k1_spectral<<<NB * NCIN, 256, 0, stream>>>(u, A1, A2, bpi);
  k2_conv<<<dim3(64, 8), 256, 0, stream>>>(bpi, Wt, out2);
  k3_recon<<<NB * NCOUT, 256, 0, stream>>>(out2, B1, B2, out);
}

// Round 9
// 442.582 us; speedup vs baseline: 3.1323x; 3.1323x over previous
//
#include <hip/hip_runtime.h>
#include <cstddef>

// PseudoSpectra2d: out = B1 @ (LocalConv3x3_posdep( pad(A1[:64]@u@A2[:64]^T) , W)) @ B2^T
// B=16, CIN=COUT=32, H=W=128, M1=M2=64, KH=KW=3, pad=1
// ws: bpi [16][32][64][64] f32 (8 MB) | out2 [16][32][64][64] f32 (8 MB)

#define NB 16
#define NCIN 32
#define NCOUT 32

typedef float f32x4 __attribute__((ext_vector_type(4)));

__device__ __forceinline__ float dpp_shr1(float x) {  // lane i <- lane i-1 (16-lane rows), edge -> 0
  int r = __builtin_amdgcn_update_dpp(0, __float_as_int(x), 0x111, 0xF, 0xF, true);
  return __int_as_float(r);
}
__device__ __forceinline__ float dpp_shl1(float x) {  // lane i <- lane i+1 (16-lane rows), edge -> 0
  int r = __builtin_amdgcn_update_dpp(0, __float_as_int(x), 0x101, 0xF, 0xF, true);
  return __int_as_float(r);
}
__device__ __forceinline__ void nt_store4(float* p, float a, float b, float c, float d) {
  f32x4 v; v.x = a; v.y = b; v.z = c; v.w = d;
  __builtin_nontemporal_store(v, (f32x4*)p);
}

// ---------------------------------------------------------------------------
// K1: per (b,c): T[h][k] = sum_w u[h][w]*A2[k][w]; bp[m][k] = sum_h A1[m][h]*T[h][k]
// Global streams (u, A1) 2-stage prefetched; A2^T / T via LDS. 512 blocks, 2/CU.
// ---------------------------------------------------------------------------
__global__ __launch_bounds__(256) void k1_spectral(const float* __restrict__ u,
                                                   const float* __restrict__ A1,
                                                   const float* __restrict__ A2,
                                                   float* __restrict__ bpi) {
  __shared__ float a2t[128 * 68];   // [w][k], stride 68
  __shared__ float t_s[128 * 68];   // [h][k], stride 68
  const int tid = threadIdx.x;
  const int bc = blockIdx.x;        // b*32 + c
  const float* up = u + (size_t)bc * 16384;

  // stage A2^T: a2t[w][k] = A2[k][w]  (k < 64)
#pragma unroll
  for (int it = 0; it < 8; ++it) {
    int f = it * 256 + tid;
    int k = f >> 5;
    int w4 = (f & 31) * 4;
    float4 v = *(const float4*)(A2 + k * 128 + w4);
    a2t[(w4 + 0) * 68 + k] = v.x;
    a2t[(w4 + 1) * 68 + k] = v.y;
    a2t[(w4 + 2) * 68 + k] = v.z;
    a2t[(w4 + 3) * 68 + k] = v.w;
  }
  __syncthreads();

  // Phase B: T[h][k], tile 8h x 4k (threads (16,16)); u prefetched 1 step ahead.
  {
    const int h0 = (tid >> 4) * 8;
    const int k0 = (tid & 15) * 4;
    float acc[8][4] = {};
    float4 uvA[8], uvB[8];
#pragma unroll
    for (int i = 0; i < 8; ++i) uvA[i] = *(const float4*)(up + (h0 + i) * 128 + 0);

#pragma unroll 1
    for (int w4 = 0; w4 < 128; w4 += 8) {
#pragma unroll
      for (int i = 0; i < 8; ++i) uvB[i] = *(const float4*)(up + (h0 + i) * 128 + w4 + 4);
      {
        float4 av[4];
#pragma unroll
        for (int dw = 0; dw < 4; ++dw) av[dw] = *(const float4*)(a2t + (w4 + dw) * 68 + k0);
#pragma unroll
        for (int i = 0; i < 8; ++i) {
          const float* up_ = (const float*)&uvA[i];
#pragma unroll
          for (int dw = 0; dw < 4; ++dw) {
            const float* ap = (const float*)&av[dw];
            float uval = up_[dw];
#pragma unroll
            for (int j = 0; j < 4; ++j) acc[i][j] += uval * ap[j];
          }
        }
      }
      if (w4 + 8 < 128) {
#pragma unroll
        for (int i = 0; i < 8; ++i) uvA[i] = *(const float4*)(up + (h0 + i) * 128 + w4 + 8);
      }
      {
        float4 av[4];
#pragma unroll
        for (int dw = 0; dw < 4; ++dw) av[dw] = *(const float4*)(a2t + (w4 + 4 + dw) * 68 + k0);
#pragma unroll
        for (int i = 0; i < 8; ++i) {
          const float* up_ = (const float*)&uvB[i];
#pragma unroll
          for (int dw = 0; dw < 4; ++dw) {
            const float* ap = (const float*)&av[dw];
            float uval = up_[dw];
#pragma unroll
            for (int j = 0; j < 4; ++j) acc[i][j] += uval * ap[j];
          }
        }
      }
    }
#pragma unroll
    for (int i = 0; i < 8; ++i)
      *(float4*)(t_s + (h0 + i) * 68 + k0) =
          make_float4(acc[i][0], acc[i][1], acc[i][2], acc[i][3]);
  }
  __syncthreads();

  // Phase C: bp[m][k], tile 4m x 4k (threads (16,16)); A1 prefetched 1 step ahead.
  {
    const int m0 = (tid >> 4) * 4;
    const int k0 = (tid & 15) * 4;
    float acc[4][4] = {};
    float4 aA[4], aB[4];
#pragma unroll
    for (int i = 0; i < 4; ++i) aA[i] = *(const float4*)(A1 + (m0 + i) * 128 + 0);

#pragma unroll 1
    for (int h4 = 0; h4 < 128; h4 += 8) {
#pragma unroll
      for (int i = 0; i < 4; ++i) aB[i] = *(const float4*)(A1 + (m0 + i) * 128 + h4 + 4);
      {
        float4 tv[4];
#pragma unroll
        for (int dh = 0; dh < 4; ++dh) tv[dh] = *(const float4*)(t_s + (h4 + dh) * 68 + k0);
#pragma unroll
        for (int i = 0; i < 4; ++i) {
          const float* ap = (const float*)&aA[i];
#pragma unroll
          for (int dh = 0; dh < 4; ++dh) {
            const float* tp = (const float*)&tv[dh];
            float aval = ap[dh];
#pragma unroll
            for (int j = 0; j < 4; ++j) acc[i][j] += aval * tp[j];
          }
        }
      }
      if (h4 + 8 < 128) {
#pragma unroll
        for (int i = 0; i < 4; ++i) aA[i] = *(const float4*)(A1 + (m0 + i) * 128 + h4 + 8);
      }
      {
        float4 tv[4];
#pragma unroll
        for (int dh = 0; dh < 4; ++dh) tv[dh] = *(const float4*)(t_s + (h4 + 4 + dh) * 68 + k0);
#pragma unroll
        for (int i = 0; i < 4; ++i) {
          const float* ap = (const float*)&aB[i];
#pragma unroll
          for (int dh = 0; dh < 4; ++dh) {
            const float* tp = (const float*)&tv[dh];
            float aval = ap[dh];
#pragma unroll
            for (int j = 0; j < 4; ++j) acc[i][j] += aval * tp[j];
          }
        }
      }
    }
    float* bp = bpi + (size_t)bc * 4096;
#pragma unroll
    for (int i = 0; i < 4; ++i)
      nt_store4(bp + (m0 + i) * 64 + k0, acc[i][0], acc[i][1], acc[i][2], acc[i][3]);
  }
}

// ---------------------------------------------------------------------------
// K2: out2[b][o][xi][xj] = sum_{c,ki,kj} xpad(b,c,xi-1+ki,xj-1+kj) * W[c*9+ki*3+kj][o][xi*64+xj]
// No LDS/barriers. W double-buffered 2-c-deep in registers (72 VGPR x 2);
// xv for both sub-iterations issued before first compute. NO launch_bounds
// wave cap (R7: (256,2) forced VGPR=128 -> scratch spill -> 4.2 GB traffic).
// Grid (64 xi XCD-swizzled, 8 og) x 256 thr; ~230 VGPR -> 2 waves/SIMD = full
// residency at 512 blocks (2 blocks/CU).
// ---------------------------------------------------------------------------
struct K2W {
  float4 wr[9][2];
};

__device__ __forceinline__ void k2_loadW(K2W& B, const float* __restrict__ Wt,
                                         int c, int xi, int o0, int xjg) {
  const float* wbase = Wt + (((size_t)c * 9) * NCOUT + o0) * 4096 + xi * 64 + xjg * 4;
#pragma unroll
  for (int t = 0; t < 9; ++t)
#pragma unroll
    for (int oo = 0; oo < 2; ++oo)
      B.wr[t][oo] = *(const float4*)(wbase + ((size_t)t * NCOUT + oo) * 4096);
}

__device__ __forceinline__ void k2_loadX(float4 xv[2][3], const float* __restrict__ bpi,
                                         int c, int xi, int b0, int xjg) {
#pragma unroll
  for (int ki = 0; ki < 3; ++ki) {
    const int row = xi - 1 + ki;
    const bool valid = (row >= 0) && (row < 64);   // wave-uniform
#pragma unroll
    for (int rb = 0; rb < 2; ++rb) {
      if (valid)
        xv[rb][ki] = *(const float4*)(bpi +
            (((size_t)(b0 + rb) * NCIN + c) * 64 + row) * 64 + xjg * 4);
      else
        xv[rb][ki] = make_float4(0.f, 0.f, 0.f, 0.f);
    }
  }
}

__device__ __forceinline__ void k2_compute(const K2W& B, const float4 xv[2][3],
                                           float acc[2][2][4]) {
#pragma unroll
  for (int ki = 0; ki < 3; ++ki) {
#pragma unroll
    for (int rb = 0; rb < 2; ++rb) {
      float xw[6];
      xw[1] = xv[rb][ki].x; xw[2] = xv[rb][ki].y;
      xw[3] = xv[rb][ki].z; xw[4] = xv[rb][ki].w;
      xw[0] = dpp_shr1(xv[rb][ki].w);   // col xj-1 (0 at left edge = pad)
      xw[5] = dpp_shl1(xv[rb][ki].x);   // col xj+4 (0 at right edge = pad)
#pragma unroll
      for (int kj = 0; kj < 3; ++kj) {
        const int t = ki * 3 + kj;
#pragma unroll
        for (int oo = 0; oo < 2; ++oo) {
          const float* w = (const float*)&B.wr[t][oo];
#pragma unroll
          for (int x = 0; x < 4; ++x)
            acc[rb][oo][x] += xw[x + kj] * w[x];
        }
      }
    }
  }
}

__global__ __launch_bounds__(256) void k2_conv(const float* __restrict__ bpi,
                                               const float* __restrict__ Wt,
                                               float* __restrict__ out2) {
  const int tid = threadIdx.x;
  const int lane = tid & 63;
  const int wv = tid >> 6;
  const int xjg = lane & 15;
  const int lbg = lane >> 4;
  const int bid = blockIdx.x;
  const int xi = ((bid & 7) << 3) | (bid >> 3);   // XCD-swizzle
  const int og = blockIdx.y;                       // 0..7
  const int bg = wv >> 1;
  const int op = wv & 1;
  const int o0 = og * 4 + op * 2;
  const int b0 = bg * 8 + lbg * 2;

  float acc[2][2][4] = {};
  K2W wA, wB;
  k2_loadW(wA, Wt, 0, xi, o0, xjg);
  k2_loadW(wB, Wt, 1, xi, o0, xjg);

#pragma unroll 1
  for (int c = 0; c < NCIN; c += 2) {
    float4 xvA[2][3], xvB[2][3];
    k2_loadX(xvA, bpi, c,     xi, b0, xjg);
    k2_loadX(xvB, bpi, c + 1, xi, b0, xjg);
    k2_compute(wA, xvA, acc);
    if (c + 2 < NCIN) k2_loadW(wA, Wt, c + 2, xi, o0, xjg);   // refill 2 iters ahead
    k2_compute(wB, xvB, acc);
    if (c + 3 < NCIN) k2_loadW(wB, Wt, c + 3, xi, o0, xjg);
  }

#pragma unroll
  for (int rb = 0; rb < 2; ++rb)
#pragma unroll
    for (int oo = 0; oo < 2; ++oo)
      nt_store4(out2 + ((size_t)(b0 + rb) * NCOUT + (o0 + oo)) * 4096 + xi * 64 + xjg * 4,
                acc[rb][oo][0], acc[rb][oo][1], acc[rb][oo][2], acc[rb][oo][3]);
}

// ---------------------------------------------------------------------------
// K3: per (b,o): T2[m][w] = sum_k out2[m][k]*B2[w][k];  R[h][w] = sum_m B1[h][m]*T2[m][w]
// out2 / B1 streams 2-stage prefetched. Phase C3 w-tile split (w0, w0+64).
// LDS 66 KB -> 2 blocks/CU.
// ---------------------------------------------------------------------------
__global__ __launch_bounds__(256) void k3_recon(const float* __restrict__ out2,
                                                const float* __restrict__ B1,
                                                const float* __restrict__ B2,
                                                float* __restrict__ outp) {
  __shared__ float b2t[64 * 132];    // [k][w], stride 132
  __shared__ float t2[64 * 132];     // [m][w], stride 132
  const int tid = threadIdx.x;
  const int bc = blockIdx.x;         // b*32 + o

  // stage B2^T: b2t[k][w] = B2[w][k]
#pragma unroll
  for (int it = 0; it < 8; ++it) {
    int f = it * 256 + tid;
    int w = f >> 4;
    int k4 = (f & 15) * 4;
    float4 v = *(const float4*)(B2 + w * 64 + k4);
    b2t[(k4 + 0) * 132 + w] = v.x;
    b2t[(k4 + 1) * 132 + w] = v.y;
    b2t[(k4 + 2) * 132 + w] = v.z;
    b2t[(k4 + 3) * 132 + w] = v.w;
  }
  __syncthreads();

  // Phase B3: T2[m][w], tile 8m x 4w (threads (8,32)); out2 prefetched.
  {
    const int m0 = (tid >> 5) * 8;
    const int w0 = (tid & 31) * 4;
    float acc[8][4] = {};
    const float* o2 = out2 + (size_t)bc * 4096;
    float4 aA[8], aB[8];
#pragma unroll
    for (int i = 0; i < 8; ++i) aA[i] = *(const float4*)(o2 + (m0 + i) * 64 + 0);

#pragma unroll 1
    for (int k4 = 0; k4 < 64; k4 += 8) {
#pragma unroll
      for (int i = 0; i < 8; ++i) aB[i] = *(const float4*)(o2 + (m0 + i) * 64 + k4 + 4);
      {
        float4 bb[4];
#pragma unroll
        for (int dk = 0; dk < 4; ++dk) bb[dk] = *(const float4*)(b2t + (k4 + dk) * 132 + w0);
#pragma unroll
        for (int i = 0; i < 8; ++i) {
          const float* ap = (const float*)&aA[i];
#pragma unroll
          for (int dk = 0; dk < 4; ++dk) {
            const float* bp = (const float*)&bb[dk];
            float aval = ap[dk];
#pragma unroll
            for (int j = 0; j < 4; ++j) acc[i][j] += aval * bp[j];
          }
        }
      }
      if (k4 + 8 < 64) {
#pragma unroll
        for (int i = 0; i < 8; ++i) aA[i] = *(const float4*)(o2 + (m0 + i) * 64 + k4 + 8);
      }
      {
        float4 bb[4];
#pragma unroll
        for (int dk = 0; dk < 4; ++dk) bb[dk] = *(const float4*)(b2t + (k4 + 4 + dk) * 132 + w0);
#pragma unroll
        for (int i = 0; i < 8; ++i) {
          const float* ap = (const float*)&aB[i];
#pragma unroll
          for (int dk = 0; dk < 4; ++dk) {
            const float* bp = (const float*)&bb[dk];
            float aval = ap[dk];
#pragma unroll
            for (int j = 0; j < 4; ++j) acc[i][j] += aval * bp[j];
          }
        }
      }
    }
    __syncthreads();
#pragma unroll
    for (int i = 0; i < 8; ++i)
      *(float4*)(t2 + (m0 + i) * 132 + w0) =
          make_float4(acc[i][0], acc[i][1], acc[i][2], acc[i][3]);
  }
  __syncthreads();

  // Phase C3: R[h][w], tile 8h x (4+4)w at (w0, w0+64) (threads (16,16)); B1 prefetched.
  {
    const int h0 = (tid >> 4) * 8;
    const int w0 = (tid & 15) * 4;       // cols w0..w0+3 and w0+64..w0+67
    float acc[8][8] = {};
    float4 aA[8], aB[8];
#pragma unroll
    for (int i = 0; i < 8; ++i) aA[i] = *(const float4*)(B1 + (h0 + i) * 64 + 0);

#pragma unroll 1
    for (int m = 0; m < 64; m += 8) {
#pragma unroll
      for (int i = 0; i < 8; ++i) aB[i] = *(const float4*)(B1 + (h0 + i) * 64 + m + 4);
      {
        float4 bb0[4], bb1[4];
#pragma unroll
        for (int dm = 0; dm < 4; ++dm) {
          bb0[dm] = *(const float4*)(t2 + (m + dm) * 132 + w0);
          bb1[dm] = *(const float4*)(t2 + (m + dm) * 132 + w0 + 64);
        }
#pragma unroll
        for (int i = 0; i < 8; ++i) {
          const float* ap = (const float*)&aA[i];
#pragma unroll
          for (int dm = 0; dm < 4; ++dm) {
            const float* b0p = (const float*)&bb0[dm];
            const float* b1p = (const float*)&bb1[dm];
            float aval = ap[dm];
#pragma unroll
            for (int j = 0; j < 4; ++j) {
              acc[i][j]     += aval * b0p[j];
              acc[i][4 + j] += aval * b1p[j];
            }
          }
        }
      }
      if (m + 8 < 64) {
#pragma unroll
        for (int i = 0; i < 8; ++i) aA[i] = *(const float4*)(B1 + (h0 + i) * 64 + m + 8);
      }
      {
        float4 bb0[4], bb1[4];
#pragma unroll
        for (int dm = 0; dm < 4; ++dm) {
          bb0[dm] = *(const float4*)(t2 + (m + 4 + dm) * 132 + w0);
          bb1[dm] = *(const float4*)(t2 + (m + 4 + dm) * 132 + w0 + 64);
        }
#pragma unroll
        for (int i = 0; i < 8; ++i) {
          const float* ap = (const float*)&aB[i];
#pragma unroll
          for (int dm = 0; dm < 4; ++dm) {
            const float* b0p = (const float*)&bb0[dm];
            const float* b1p = (const float*)&bb1[dm];
            float aval = ap[dm];
#pragma unroll
            for (int j = 0; j < 4; ++j) {
              acc[i][j]     += aval * b0p[j];
              acc[i][4 + j] += aval * b1p[j];
            }
          }
        }
      }
    }
    float* rp = outp + (size_t)bc * 16384;
#pragma unroll
    for (int i = 0; i < 8; ++i) {
      *(float4*)(rp + (h0 + i) * 128 + w0) =
          make_float4(acc[i][0], acc[i][1], acc[i][2], acc[i][3]);
      *(float4*)(rp + (h0 + i) * 128 + w0 + 64) =
          make_float4(acc[i][4], acc[i][5], acc[i][6], acc[i][7]);
    }
  }
}

extern "C" void kernel_launch(void* const* d_in, const int* in_sizes, int n_in,
                              void* d_out, int out_size, void* d_ws, size_t ws_size,
                              hipStream_t stream) {
  (void)in_sizes; (void)n_in; (void)out_size; (void)ws_size;
  const float* u  = (const float*)d_in[0];
  const float* A1 = (const float*)d_in[1];
  const float* A2 = (const float*)d_in[2];
  const float* B1 = (const float*)d_in[3];
  const float* B2 = (const float*)d_in[4];
  const float* Wt = (const float*)d_in[5];
  float* out = (float*)d_out;

  const size_t SEG = (size_t)NB * NCIN * 4096 * sizeof(float);   // 8 MB
  float* bpi  = (float*)d_ws;
  float* out2 = (float*)((char*)d_ws + SEG);

  k1_spectral<<<NB * NCIN, 256, 0, stream>>>(u, A1, A2, bpi);
  k2_conv<<<dim3(64, 8), 256, 0, stream>>>(bpi, Wt, out2);
  k3_recon<<<NB * NCOUT, 256, 0, stream>>>(out2, B1, B2, out);
}